// Round 14
// baseline (68.370 us; speedup 1.0000x reference)
//
#include <hip/hip_runtime.h>
#include <stdint.h>
#include <stddef.h>

typedef short s16x4 __attribute__((ext_vector_type(4)));
typedef short s16x8 __attribute__((ext_vector_type(8)));
typedef float f32x4 __attribute__((ext_vector_type(4)));

#define NN 8192
#define DD 512
#define PP 128
#define HH 128

// round-to-nearest-even f32 -> bf16 (bits in a short)
__device__ __forceinline__ short f2bf(float f) {
  unsigned u = __builtin_bit_cast(unsigned, f);
  u = (u + 0x7fffu + ((u >> 16) & 1u)) >> 16;
  return (short)u;
}

// async global->LDS, 16B per lane. LDS dest is wave-uniform base; HW adds lane*16.
__device__ __forceinline__ void async16(const void* g, void* l) {
  __builtin_amdgcn_global_load_lds(
      (const __attribute__((address_space(1))) unsigned int*)g,
      (__attribute__((address_space(3))) unsigned int*)l, 16, 0, 0);
}

// ---- 2-phase double-buffered (MF*32) x 128 bf16 GEMM core. 256 threads = 4 waves 2x2. ----
// A: [.][lda] row-major (K contiguous). BT: [.][ldb] row-major = B^T (K contiguous).
template <int MF>
__device__ __forceinline__ void gemm_core2(
    const short* __restrict__ A, long lda,
    const short* __restrict__ BT, long ldb,
    long rowBase, long colBase, int k0, int k1,
    short* As0, short* Bs0, short* As1, short* Bs1,
    f32x4 (*acc)[4]) {
  const int tid  = threadIdx.x;
  const int lane = tid & 63;
  const int wid  = tid >> 6;
  const int wr   = (wid >> 1) * (MF * 16);
  const int wc   = (wid & 1) * 64;
  const int srow = lane >> 3;
  const int skk  = (lane & 7) * 8;

#define STAGE_(AS, BS, KK)                                                    \
  do {                                                                        \
    _Pragma("unroll")                                                         \
    for (int it = 0; it < MF; ++it) {                                         \
      int r = wid * (MF * 8) + it * 8;                                        \
      async16(A + (rowBase + r + srow) * lda + (KK) + skk, (AS) + r * 64);    \
    }                                                                         \
    _Pragma("unroll")                                                         \
    for (int it = 0; it < 4; ++it) {                                          \
      int r = wid * 32 + it * 8;                                              \
      async16(BT + (colBase + r + srow) * ldb + (KK) + skk, (BS) + r * 64);   \
    }                                                                         \
  } while (0)

  STAGE_(As0, Bs0, k0);
  __syncthreads();
  for (int k = k0; k < k1; k += 64) {
    if (k + 64 < k1) STAGE_(As1, Bs1, k + 64);
#pragma unroll
    for (int ks = 0; ks < 64; ks += 32) {
      s16x8 af[MF], bfv[4];
#pragma unroll
      for (int i = 0; i < MF; ++i)
        af[i]  = *(const s16x8*)(As0 + (wr + i * 16 + (lane & 15)) * 64 + ks + (lane >> 4) * 8);
#pragma unroll
      for (int i = 0; i < 4; ++i)
        bfv[i] = *(const s16x8*)(Bs0 + (wc + i * 16 + (lane & 15)) * 64 + ks + (lane >> 4) * 8);
#pragma unroll
      for (int mi = 0; mi < MF; ++mi)
#pragma unroll
        for (int ni = 0; ni < 4; ++ni)
          acc[mi][ni] = __builtin_amdgcn_mfma_f32_16x16x32_bf16(af[mi], bfv[ni], acc[mi][ni], 0, 0, 0);
    }
    __syncthreads();
    short* t0 = As0; As0 = As1; As1 = t0;
    short* t1 = Bs0; Bs0 = Bs1; Bs1 = t1;
  }
#undef STAGE_
}

__device__ __forceinline__ void zero_acc2(f32x4 (*acc)[4], int mf) {
  f32x4 z = {0.f, 0.f, 0.f, 0.f};
  for (int i = 0; i < mf; ++i)
    for (int j = 0; j < 4; ++j) acc[i][j] = z;
}

// ---------------- prep: fp32 -> bf16 conversions (+ weight transposes) ----------------
__global__ __launch_bounds__(256) void k_prep(
    const float* __restrict__ x1, const float* __restrict__ w1,
    const float* __restrict__ w2, const float* __restrict__ gcw,
    short* __restrict__ x1b, short* __restrict__ w1t,
    short* __restrict__ w2t, short* __restrict__ gcwt) {
  long b = blockIdx.x;
  int t = threadIdx.x;
  if (b < 4096) {                       // x1: 4M floats, 4 per thread
    long i = b * 256 + t;
    float4 v = ((const float4*)x1)[i];
    s16x4 o;
    o[0] = f2bf(v.x); o[1] = f2bf(v.y); o[2] = f2bf(v.z); o[3] = f2bf(v.w);
    *(s16x4*)(x1b + i * 4) = o;
  } else if (b < 4096 + 1024) {         // w1t[n*512+k] = w1[k*512+n]
    long i = (b - 4096) * 256 + t;
    int n = (int)(i >> 9), k = (int)(i & 511);
    w1t[i] = f2bf(w1[(long)k * DD + n]);
  } else if (b < 4096 + 1024 + 256) {   // w2t[n*512+k] = w2[k*128+n]
    long i = (b - 5120) * 256 + t;
    int n = (int)(i >> 9), k = (int)(i & 511);
    w2t[i] = f2bf(w2[(long)k * PP + n]);
  } else {                              // gcwt[n*512+k] = gcw[k*128+n]
    long i = (b - 5376) * 256 + t;
    int n = (int)(i >> 9), k = (int)(i & 511);
    gcwt[i] = f2bf(gcw[(long)k * HH + n]);
  }
}

// ---------------- merged GEMM1 (relu(x1@W1)) + GEMM3 (h^T = (x1@gc_w)^T) ----------------
// blocks [0,512): g1 tiles 64x128.  blocks [512,640): g3 tiles 64x128 -> hT.
__global__ __launch_bounds__(256) void k_g13(const short* __restrict__ x1b,
                                             const short* __restrict__ w1t,
                                             const short* __restrict__ gcwt,
                                             short* __restrict__ Y,
                                             short* __restrict__ hT) {
  __shared__ __align__(16) char smem[49152];
  short* As0 = (short*)smem;                    // 8KB  (64x64)
  short* As1 = (short*)(smem + 8192);           // 8KB
  short* Bs0 = (short*)(smem + 16384);          // 16KB (128x64)
  short* Bs1 = (short*)(smem + 32768);          // 16KB
  f32x4 acc[2][4];
  zero_acc2(acc, 2);
  const int bx = blockIdx.x;
  const int lane = threadIdx.x & 63, wid = threadIdx.x >> 6;
  const int wr = (wid >> 1) * 32, wc = (wid & 1) * 64;
  if (bx < 512) {
    long rowBase = (long)(bx >> 2) * 64;
    long colBase = (long)(bx & 3) * 128;
    gemm_core2<2>(x1b, DD, w1t, DD, rowBase, colBase, 0, DD, As0, Bs0, As1, Bs1, acc);
#pragma unroll
    for (int mi = 0; mi < 2; ++mi)
#pragma unroll
      for (int ni = 0; ni < 4; ++ni)
#pragma unroll
        for (int r = 0; r < 4; ++r) {
          long m = rowBase + wr + mi * 16 + ((lane >> 4) << 2) + r;
          long n = colBase + wc + ni * 16 + (lane & 15);
          float v = acc[mi][ni][r];
          Y[m * DD + n] = f2bf(v > 0.f ? v : 0.f);
        }
  } else {
    long rowBase = (long)(bx - 512) * 64;
    gemm_core2<2>(x1b, DD, gcwt, DD, rowBase, 0, 0, DD, As0, Bs0, As1, Bs1, acc);
    // transpose through LDS for coalesced hT writes (overlay staging; k-loop's
    // trailing barrier separates the last reads from these writes)
    short (*hs)[66] = (short(*)[66])smem;       // 128x66x2 = 16.9KB
#pragma unroll
    for (int mi = 0; mi < 2; ++mi)
#pragma unroll
      for (int ni = 0; ni < 4; ++ni)
#pragma unroll
        for (int r = 0; r < 4; ++r) {
          int m = wr + mi * 16 + ((lane >> 4) << 2) + r;
          int n = wc + ni * 16 + (lane & 15);
          hs[n][m] = f2bf(acc[mi][ni][r]);
        }
    __syncthreads();
    int t = threadIdx.x;
    int h = t >> 1, m0 = (t & 1) * 32;
#pragma unroll
    for (int j0 = 0; j0 < 32; j0 += 8) {
      s16x8 o;
#pragma unroll
      for (int u = 0; u < 8; ++u) o[u] = hs[h][m0 + j0 + u];
      *(s16x8*)(hT + (long)h * NN + rowBase + m0 + j0) = o;
    }
  }
}

// ------- fused GEMM2 + split-K G-chunk + G-reduction: per 64-row block -----------
// x_proj = Y @ W2 -> xs (LDS); norms; xp; xpt_s; stage hT tile; Gp[bid] = xpt @ hts;
// then signal (release atomicAdd) + load-poll until all 128 Gp written, and each
// block reduces its 128-element slice of G -> GT (replaces the k_red kernel).
__global__ __launch_bounds__(256) void k_g2e(const short* __restrict__ Y,
                                             const short* __restrict__ w2t,
                                             const short* __restrict__ hT,
                                             short* __restrict__ xp,
                                             float* __restrict__ invnw,
                                             float* __restrict__ Gp,
                                             short* __restrict__ GT,
                                             unsigned* __restrict__ cnt) {
  __shared__ __align__(16) char smem[50176];
  short* As0 = (short*)smem;                 // staging: [0, 49152)
  short* As1 = (short*)(smem + 8192);
  short* Bs0 = (short*)(smem + 16384);
  short* Bs1 = (short*)(smem + 32768);
  f32x4 acc[2][4];
  zero_acc2(acc, 2);
  const long rowBase = (long)blockIdx.x * 64;
  gemm_core2<2>(Y, DD, w2t, DD, rowBase, 0, 0, DD, As0, Bs0, As1, Bs1, acc);
  const int t = threadIdx.x;
  const int lane = t & 63, wid = t >> 6;
  {
    const int wr = (wid >> 1) * 32, wc = (wid & 1) * 64;
    float (*xs)[129] = (float(*)[129])smem;         // [0, 33024)
    float* invw_s = (float*)(smem + 49920);         // [49920, 50176)
    short* xpt_s = (short*)(smem + 33536);          // [33536, 49920)  [128p][64n]
#pragma unroll
    for (int mi = 0; mi < 2; ++mi)
#pragma unroll
      for (int ni = 0; ni < 4; ++ni)
#pragma unroll
        for (int r = 0; r < 4; ++r)
          xs[wr + mi * 16 + ((lane >> 4) << 2) + r][wc + ni * 16 + (lane & 15)] = acc[mi][ni][r];
    __syncthreads();
    if (t < 64) {  // fp32 row norm over P=128
      float s = 0.f;
#pragma unroll 8
      for (int i = 0; i < 128; ++i) { int c = (t + i) & 127; float v = xs[t][c]; s += v * v; }
      float nr = sqrtf(s);
      invnw[rowBase + t] = 1.f / (8192.f * nr);
      invw_s[t] = 1.f / nr;
    }
    __syncthreads();
    // xp [N][P] coalesced global write
#pragma unroll
    for (int i = 0; i < 4; ++i) {
      int seg = i * 256 + t;
      int r = seg >> 4, c0 = (seg & 15) * 8;
      s16x8 o;
#pragma unroll
      for (int u = 0; u < 8; ++u) o[u] = f2bf(xs[r][c0 + u]);
      *(s16x8*)(xp + (long)(rowBase + r) * PP + c0) = o;
    }
    // xpt_s[p][n] = xs[n][p] / w[n]  (LDS only — no global xpT)
    int c = t >> 1, n0 = (t & 1) * 32;
#pragma unroll
    for (int j0 = 0; j0 < 32; j0 += 8) {
      s16x8 o;
#pragma unroll
      for (int u = 0; u < 8; ++u) {
        int n = n0 + j0 + u;
        o[u] = f2bf(xs[n][c] * invw_s[n]);
      }
      *(s16x8*)(xpt_s + c * 64 + n0 + j0) = o;
    }
  }
  __syncthreads();
  // stage hT tile [128h][64n] into [0,16384) (xs dead now)
  {
    short* hts = (short*)smem;
    const int srow = lane >> 3, skk = (lane & 7) * 8;
#pragma unroll
    for (int it = 0; it < 4; ++it) {
      int r = wid * 32 + it * 8;
      async16(hT + (long)(r + srow) * NN + rowBase + skk, hts + r * 64);
    }
  }
  __syncthreads();
  // Gp[bid] = xpt_s[128x64] @ hts^T-form  (m=p, n=h, k=64 -> 2 ks-steps)
  {
    const short* xpt_s = (const short*)(smem + 33536);
    const short* hts = (const short*)smem;
    const int wr = (wid >> 1) * 64, wc = (wid & 1) * 64;
    f32x4 acc2[4][4];
    zero_acc2(acc2, 4);
#pragma unroll
    for (int ks = 0; ks < 64; ks += 32) {
      s16x8 af[4], bfv[4];
#pragma unroll
      for (int i = 0; i < 4; ++i)
        af[i]  = *(const s16x8*)(xpt_s + (wr + i * 16 + (lane & 15)) * 64 + ks + (lane >> 4) * 8);
#pragma unroll
      for (int i = 0; i < 4; ++i)
        bfv[i] = *(const s16x8*)(hts + (wc + i * 16 + (lane & 15)) * 64 + ks + (lane >> 4) * 8);
#pragma unroll
      for (int mi = 0; mi < 4; ++mi)
#pragma unroll
        for (int ni = 0; ni < 4; ++ni)
          acc2[mi][ni] = __builtin_amdgcn_mfma_f32_16x16x32_bf16(af[mi], bfv[ni], acc2[mi][ni], 0, 0, 0);
    }
    float* gp = Gp + (long)blockIdx.x * (PP * HH);
#pragma unroll
    for (int mi = 0; mi < 4; ++mi)
#pragma unroll
      for (int ni = 0; ni < 4; ++ni)
#pragma unroll
        for (int r = 0; r < 4; ++r) {
          int m = wr + mi * 16 + ((lane >> 4) << 2) + r;
          int n = wc + ni * 16 + (lane & 15);
          gp[m * HH + n] = acc2[mi][ni][r];
        }
  }
  // ---- fused k_red: release-signal, LOAD-poll (no RMW convoy), slice-reduce ----
  __syncthreads();                 // all gp stores issued block-wide
  if (t == 0) {
    __threadfence();               // flush Gp to device scope (cross-XCD visible)
    atomicAdd(cnt, 1u);            // one RMW per block (release signal)
    while (__hip_atomic_load(cnt, __ATOMIC_RELAXED, __HIP_MEMORY_SCOPE_AGENT) < 128u)
      __builtin_amdgcn_s_sleep(8); // poll with loads: no cacheline serialization
  }
  __syncthreads();
  __threadfence();                 // acquire side
  if (t < 128) {
    int i = blockIdx.x * 128 + t;  // i = p*128 + h; coalesced across t
    float s = 0.f;
#pragma unroll 8
    for (int j = 0; j < 128; ++j) s += Gp[j * (PP * HH) + i];
    int p = i >> 7, h = i & 127;
    GT[h * PP + p] = f2bf(s);
  }
}

// ---------------- final: out = (xp @ G) * invnw[row] + gc_b ----------------
__global__ __launch_bounds__(256) void k_gf(const short* __restrict__ xp,
                                            const short* __restrict__ GT,
                                            const float* __restrict__ invnw,
                                            const float* __restrict__ gcb,
                                            float* __restrict__ out) {
  __shared__ __align__(16) char smem[49152];
  short* As0 = (short*)smem;
  short* As1 = (short*)(smem + 8192);
  short* Bs0 = (short*)(smem + 16384);
  short* Bs1 = (short*)(smem + 32768);
  f32x4 acc[2][4];
  zero_acc2(acc, 2);
  long rowBase = (long)blockIdx.x * 64;
  gemm_core2<2>(xp, PP, GT, PP, rowBase, 0, 0, PP, As0, Bs0, As1, Bs1, acc);
  const int lane = threadIdx.x & 63, wid = threadIdx.x >> 6;
  const int wr = (wid >> 1) * 32, wc = (wid & 1) * 64;
#pragma unroll
  for (int mi = 0; mi < 2; ++mi)
#pragma unroll
    for (int ni = 0; ni < 4; ++ni)
#pragma unroll
      for (int r = 0; r < 4; ++r) {
        long m = rowBase + wr + mi * 16 + ((lane >> 4) << 2) + r;
        int n = wc + ni * 16 + (lane & 15);
        out[m * HH + n] = acc[mi][ni][r] * invnw[m] + gcb[n];
      }
}

extern "C" void kernel_launch(void* const* d_in, const int* in_sizes, int n_in,
                              void* d_out, int out_size, void* d_ws, size_t ws_size,
                              hipStream_t stream) {
  const float* x1  = (const float*)d_in[0];
  const float* w1  = (const float*)d_in[1];
  const float* w2  = (const float*)d_in[2];
  const float* gcw = (const float*)d_in[3];
  const float* gcb = (const float*)d_in[4];
  float* out = (float*)d_out;

  char* ws = (char*)d_ws;
  size_t off = 0;
  auto alloc = [&](size_t bytes) -> char* {
    char* p = ws + off;
    off += (bytes + 255) & ~(size_t)255;
    return p;
  };
  short* x1b  = (short*)alloc((size_t)NN * DD * 2);
  short* w1t  = (short*)alloc((size_t)DD * DD * 2);
  short* w2t  = (short*)alloc((size_t)PP * DD * 2);
  short* gcwt = (short*)alloc((size_t)HH * DD * 2);
  short* Y    = (short*)alloc((size_t)NN * DD * 2);
  short* xp   = (short*)alloc((size_t)NN * PP * 2);
  short* hT   = (short*)alloc((size_t)NN * HH * 2);
  float* invnw = (float*)alloc((size_t)NN * 4);
  float* Gp   = (float*)alloc((size_t)128 * PP * HH * 4);
  short* GT   = (short*)alloc((size_t)PP * HH * 2);
  unsigned* cnt = (unsigned*)alloc(256);

  hipMemsetAsync(cnt, 0, 8, stream);
  hipLaunchKernelGGL(k_prep, dim3(5632), dim3(256), 0, stream,
                     x1, w1, w2, gcw, x1b, w1t, w2t, gcwt);
  hipLaunchKernelGGL(k_g13, dim3(640), dim3(256), 0, stream, x1b, w1t, gcwt, Y, hT);
  hipLaunchKernelGGL(k_g2e, dim3(128), dim3(256), 0, stream, Y, w2t, hT, xp, invnw, Gp, GT, cnt);
  hipLaunchKernelGGL(k_gf, dim3(128), dim3(256), 0, stream, xp, GT, invnw, gcb, out);
}

// Round 15
// 53.002 us; speedup vs baseline: 1.2900x; 1.2900x over previous
//
#include <hip/hip_runtime.h>
#include <stdint.h>
#include <stddef.h>

typedef short s16x4 __attribute__((ext_vector_type(4)));
typedef short s16x8 __attribute__((ext_vector_type(8)));
typedef float f32x4 __attribute__((ext_vector_type(4)));

#define NN 8192
#define DD 512
#define PP 128
#define HH 128

// round-to-nearest-even f32 -> bf16 (bits in a short)
__device__ __forceinline__ short f2bf(float f) {
  unsigned u = __builtin_bit_cast(unsigned, f);
  u = (u + 0x7fffu + ((u >> 16) & 1u)) >> 16;
  return (short)u;
}

// async global->LDS, 16B per lane. LDS dest is wave-uniform base; HW adds lane*16.
__device__ __forceinline__ void async16(const void* g, void* l) {
  __builtin_amdgcn_global_load_lds(
      (const __attribute__((address_space(1))) unsigned int*)g,
      (__attribute__((address_space(3))) unsigned int*)l, 16, 0, 0);
}

// ---- 2-phase double-buffered (MF*32) x 128 bf16 GEMM core. 256 threads = 4 waves 2x2. ----
// A: [.][lda] row-major (K contiguous). BT: [.][ldb] row-major = B^T (K contiguous).
// MF=1: 32-row tile, wave quadrant 16x64. MF=2: 64-row. MF=4: 128-row.
template <int MF>
__device__ __forceinline__ void gemm_core2(
    const short* __restrict__ A, long lda,
    const short* __restrict__ BT, long ldb,
    long rowBase, long colBase, int k0, int k1,
    short* As0, short* Bs0, short* As1, short* Bs1,
    f32x4 (*acc)[4]) {
  const int tid  = threadIdx.x;
  const int lane = tid & 63;
  const int wid  = tid >> 6;
  const int wr   = (wid >> 1) * (MF * 16);
  const int wc   = (wid & 1) * 64;
  const int srow = lane >> 3;
  const int skk  = (lane & 7) * 8;

#define STAGE_(AS, BS, KK)                                                    \
  do {                                                                        \
    _Pragma("unroll")                                                         \
    for (int it = 0; it < MF; ++it) {                                         \
      int r = wid * (MF * 8) + it * 8;                                        \
      async16(A + (rowBase + r + srow) * lda + (KK) + skk, (AS) + r * 64);    \
    }                                                                         \
    _Pragma("unroll")                                                         \
    for (int it = 0; it < 4; ++it) {                                          \
      int r = wid * 32 + it * 8;                                              \
      async16(BT + (colBase + r + srow) * ldb + (KK) + skk, (BS) + r * 64);   \
    }                                                                         \
  } while (0)

  STAGE_(As0, Bs0, k0);
  __syncthreads();
  for (int k = k0; k < k1; k += 64) {
    if (k + 64 < k1) STAGE_(As1, Bs1, k + 64);
#pragma unroll
    for (int ks = 0; ks < 64; ks += 32) {
      s16x8 af[MF], bfv[4];
#pragma unroll
      for (int i = 0; i < MF; ++i)
        af[i]  = *(const s16x8*)(As0 + (wr + i * 16 + (lane & 15)) * 64 + ks + (lane >> 4) * 8);
#pragma unroll
      for (int i = 0; i < 4; ++i)
        bfv[i] = *(const s16x8*)(Bs0 + (wc + i * 16 + (lane & 15)) * 64 + ks + (lane >> 4) * 8);
#pragma unroll
      for (int mi = 0; mi < MF; ++mi)
#pragma unroll
        for (int ni = 0; ni < 4; ++ni)
          acc[mi][ni] = __builtin_amdgcn_mfma_f32_16x16x32_bf16(af[mi], bfv[ni], acc[mi][ni], 0, 0, 0);
    }
    __syncthreads();
    short* t0 = As0; As0 = As1; As1 = t0;
    short* t1 = Bs0; Bs0 = Bs1; Bs1 = t1;
  }
#undef STAGE_
}

__device__ __forceinline__ void zero_acc2(f32x4 (*acc)[4], int mf) {
  f32x4 z = {0.f, 0.f, 0.f, 0.f};
  for (int i = 0; i < mf; ++i)
    for (int j = 0; j < 4; ++j) acc[i][j] = z;
}

// ---------------- prep: x1 fp32->bf16 (coalesced) + weights via LDS transpose ----------------
// grid 4192: [0,4096) x1; [4096,4160) w1 tiles; [4160,4176) w2; [4176,4192) gcw.
__global__ __launch_bounds__(256) void k_prep(
    const float* __restrict__ x1, const float* __restrict__ w1,
    const float* __restrict__ w2, const float* __restrict__ gcw,
    short* __restrict__ x1b, short* __restrict__ w1t,
    short* __restrict__ w2t, short* __restrict__ gcwt) {
  __shared__ float tile[64][65];
  long b = blockIdx.x;
  int t = threadIdx.x;
  if (b < 4096) {                       // x1: 4M floats, 4 per thread
    long i = b * 256 + t;
    float4 v = ((const float4*)x1)[i];
    s16x4 o;
    o[0] = f2bf(v.x); o[1] = f2bf(v.y); o[2] = f2bf(v.z); o[3] = f2bf(v.w);
    *(s16x4*)(x1b + i * 4) = o;
    return;
  }
  int bb = (int)(b - 4096);
  const float* src; short* dst; int K0, N0, ldn;
  if (bb < 64)      { src = w1;  dst = w1t;  ldn = 512; K0 = (bb >> 3) * 64; N0 = (bb & 7) * 64; }
  else if (bb < 80) { int c = bb - 64; src = w2;  dst = w2t;  ldn = 128; K0 = (c >> 1) * 64; N0 = (c & 1) * 64; }
  else              { int c = bb - 80; src = gcw; dst = gcwt; ldn = 128; K0 = (c >> 1) * 64; N0 = (c & 1) * 64; }
#pragma unroll
  for (int i = 0; i < 4; ++i) {
    int idx = i * 1024 + t * 4;            // coalesced float4 reads of src rows
    int row = idx >> 6, col = idx & 63;
    float4 v = *(const float4*)(src + (long)(K0 + row) * ldn + N0 + col);
    tile[row][col] = v.x; tile[row][col + 1] = v.y;
    tile[row][col + 2] = v.z; tile[row][col + 3] = v.w;
  }
  __syncthreads();
#pragma unroll
  for (int i = 0; i < 4; ++i) {
    int idx = i * 1024 + t * 4;
    int n = idx >> 6, k = idx & 63;        // dst[n][k] = src[k][n]
    s16x4 o;
#pragma unroll
    for (int u = 0; u < 4; ++u) o[u] = f2bf(tile[k + u][n]);
    *(s16x4*)(dst + (long)(N0 + n) * DD + K0 + k) = o;
  }
}

// ---------------- merged GEMM1 (relu(x1@W1)) + GEMM3 (h^T = (x1@gc_w)^T) ----------------
// blocks [0,512): g1 tiles 64x128.  blocks [512,640): g3 tiles 64x128 -> hT.  (verbatim R8)
__global__ __launch_bounds__(256) void k_g13(const short* __restrict__ x1b,
                                             const short* __restrict__ w1t,
                                             const short* __restrict__ gcwt,
                                             short* __restrict__ Y,
                                             short* __restrict__ hT) {
  __shared__ __align__(16) char smem[49152];
  short* As0 = (short*)smem;                    // 8KB  (64x64)
  short* As1 = (short*)(smem + 8192);           // 8KB
  short* Bs0 = (short*)(smem + 16384);          // 16KB (128x64)
  short* Bs1 = (short*)(smem + 32768);          // 16KB
  f32x4 acc[2][4];
  zero_acc2(acc, 2);
  const int bx = blockIdx.x;
  const int lane = threadIdx.x & 63, wid = threadIdx.x >> 6;
  const int wr = (wid >> 1) * 32, wc = (wid & 1) * 64;
  if (bx < 512) {
    long rowBase = (long)(bx >> 2) * 64;
    long colBase = (long)(bx & 3) * 128;
    gemm_core2<2>(x1b, DD, w1t, DD, rowBase, colBase, 0, DD, As0, Bs0, As1, Bs1, acc);
#pragma unroll
    for (int mi = 0; mi < 2; ++mi)
#pragma unroll
      for (int ni = 0; ni < 4; ++ni)
#pragma unroll
        for (int r = 0; r < 4; ++r) {
          long m = rowBase + wr + mi * 16 + ((lane >> 4) << 2) + r;
          long n = colBase + wc + ni * 16 + (lane & 15);
          float v = acc[mi][ni][r];
          Y[m * DD + n] = f2bf(v > 0.f ? v : 0.f);
        }
  } else {
    long rowBase = (long)(bx - 512) * 64;
    gemm_core2<2>(x1b, DD, gcwt, DD, rowBase, 0, 0, DD, As0, Bs0, As1, Bs1, acc);
    short (*hs)[66] = (short(*)[66])smem;       // 128x66x2 = 16.9KB (overlay)
#pragma unroll
    for (int mi = 0; mi < 2; ++mi)
#pragma unroll
      for (int ni = 0; ni < 4; ++ni)
#pragma unroll
        for (int r = 0; r < 4; ++r) {
          int m = wr + mi * 16 + ((lane >> 4) << 2) + r;
          int n = wc + ni * 16 + (lane & 15);
          hs[n][m] = f2bf(acc[mi][ni][r]);
        }
    __syncthreads();
    int t = threadIdx.x;
    int h = t >> 1, m0 = (t & 1) * 32;
#pragma unroll
    for (int j0 = 0; j0 < 32; j0 += 8) {
      s16x8 o;
#pragma unroll
      for (int u = 0; u < 8; ++u) o[u] = hs[h][m0 + j0 + u];
      *(s16x8*)(hT + (long)h * NN + rowBase + m0 + j0) = o;
    }
  }
}

// ------- fused GEMM2 + split-K G-chunk: 32-row tiles, 256 blocks (full CU coverage) -------
__global__ __launch_bounds__(256) void k_g2e(const short* __restrict__ Y,
                                             const short* __restrict__ w2t,
                                             const short* __restrict__ hT,
                                             short* __restrict__ xp,
                                             float* __restrict__ invnw,
                                             float* __restrict__ Gp) {
  __shared__ __align__(16) char smem[41216];
  short* As0 = (short*)smem;                 // 4KB (32x64)
  short* As1 = (short*)(smem + 4096);
  short* Bs0 = (short*)(smem + 8192);        // 16KB (128x64)
  short* Bs1 = (short*)(smem + 24576);
  f32x4 acc[1][4];
  zero_acc2(acc, 1);
  const long rowBase = (long)blockIdx.x * 32;
  gemm_core2<1>(Y, DD, w2t, DD, rowBase, 0, 0, DD, As0, Bs0, As1, Bs1, acc);
  const int t = threadIdx.x;
  const int lane = t & 63, wid = t >> 6;
  {
    const int wr = (wid >> 1) * 16, wc = (wid & 1) * 64;
    float (*xs)[129] = (float(*)[129])smem;         // [0, 16512)
    short* xpt_s = (short*)(smem + 16640);          // [16640, 24832)  [128p][32n]
    float* invw_s = (float*)(smem + 40960);         // [40960, 41088)
#pragma unroll
    for (int ni = 0; ni < 4; ++ni)
#pragma unroll
      for (int r = 0; r < 4; ++r)
        xs[wr + ((lane >> 4) << 2) + r][wc + ni * 16 + (lane & 15)] = acc[0][ni][r];
    __syncthreads();
    if (t < 32) {  // fp32 row norm over P=128
      float s = 0.f;
#pragma unroll 8
      for (int i = 0; i < 128; ++i) { int c = (t + i) & 127; float v = xs[t][c]; s += v * v; }
      float nr = sqrtf(s);
      invnw[rowBase + t] = 1.f / (8192.f * nr);
      invw_s[t] = 1.f / nr;
    }
    __syncthreads();
    // xp [N][P] coalesced global write (32x128 = 512 segs of 8)
#pragma unroll
    for (int i = 0; i < 2; ++i) {
      int seg = i * 256 + t;
      int r = seg >> 4, c0 = (seg & 15) * 8;
      s16x8 o;
#pragma unroll
      for (int u = 0; u < 8; ++u) o[u] = f2bf(xs[r][c0 + u]);
      *(s16x8*)(xp + (long)(rowBase + r) * PP + c0) = o;
    }
    // xpt_s[p][n] = xs[n][p] / w[n]
    int c = t >> 1, n0 = (t & 1) * 16;
#pragma unroll
    for (int j0 = 0; j0 < 16; j0 += 8) {
      s16x8 o;
#pragma unroll
      for (int u = 0; u < 8; ++u) {
        int n = n0 + j0 + u;
        o[u] = f2bf(xs[n][c] * invw_s[n]);
      }
      *(s16x8*)(xpt_s + c * 32 + n0 + j0) = o;
    }
  }
  __syncthreads();
  // stage hT tile [128h][32n] into [32768, 40960) (Bs1 dead)
  {
    short* hts = (short*)(smem + 32768);
#pragma unroll
    for (int it = 0; it < 2; ++it) {
      int r = wid * 32 + it * 16;
      async16(hT + (long)(r + (lane >> 2)) * NN + rowBase + (lane & 3) * 8, hts + r * 32);
    }
  }
  __syncthreads();
  // Gp[bid] = xpt_s[128x32] @ hts (m=p, n=h, k=32 -> 1 ks-step)
  {
    const short* xpt_s = (const short*)(smem + 16640);
    const short* hts = (const short*)(smem + 32768);
    const int wr = (wid >> 1) * 64, wc = (wid & 1) * 64;
    f32x4 acc2[4][4];
    zero_acc2(acc2, 4);
    s16x8 af[4], bfv[4];
#pragma unroll
    for (int i = 0; i < 4; ++i)
      af[i]  = *(const s16x8*)(xpt_s + (wr + i * 16 + (lane & 15)) * 32 + (lane >> 4) * 8);
#pragma unroll
    for (int i = 0; i < 4; ++i)
      bfv[i] = *(const s16x8*)(hts + (wc + i * 16 + (lane & 15)) * 32 + (lane >> 4) * 8);
#pragma unroll
    for (int mi = 0; mi < 4; ++mi)
#pragma unroll
      for (int ni = 0; ni < 4; ++ni)
        acc2[mi][ni] = __builtin_amdgcn_mfma_f32_16x16x32_bf16(af[mi], bfv[ni], acc2[mi][ni], 0, 0, 0);
    float* gp = Gp + (long)blockIdx.x * (PP * HH);
#pragma unroll
    for (int mi = 0; mi < 4; ++mi)
#pragma unroll
      for (int ni = 0; ni < 4; ++ni)
#pragma unroll
        for (int r = 0; r < 4; ++r) {
          int m = wr + mi * 16 + ((lane >> 4) << 2) + r;
          int n = wc + ni * 16 + (lane & 15);
          gp[m * HH + n] = acc2[mi][ni][r];
        }
  }
}

// ---------------- reduce partials -> G^T bf16 [H][P]: 128 blocks x 128 threads ----------------
__global__ __launch_bounds__(128) void k_red(const float* __restrict__ Gp,
                                             short* __restrict__ GT) {
  int i = blockIdx.x * 128 + threadIdx.x;  // i = p*128 + h
  float s = 0.f;
#pragma unroll 8
  for (int j = 0; j < 256; ++j) s += Gp[j * (PP * HH) + i];
  int p = i >> 7, h = i & 127;
  GT[h * PP + p] = f2bf(s);
}

// ---------------- final: out = (xp @ G) * invnw[row] + gc_b: 32-row tiles, 256 blocks ----------------
__global__ __launch_bounds__(256) void k_gf(const short* __restrict__ xp,
                                            const short* __restrict__ GT,
                                            const float* __restrict__ invnw,
                                            const float* __restrict__ gcb,
                                            float* __restrict__ out) {
  __shared__ __align__(16) char smem[40960];
  short* As0 = (short*)smem;                 // 4KB
  short* As1 = (short*)(smem + 4096);
  short* Bs0 = (short*)(smem + 8192);        // 16KB
  short* Bs1 = (short*)(smem + 24576);
  f32x4 acc[1][4];
  zero_acc2(acc, 1);
  long rowBase = (long)blockIdx.x * 32;
  gemm_core2<1>(xp, PP, GT, PP, rowBase, 0, 0, PP, As0, Bs0, As1, Bs1, acc);
  const int lane = threadIdx.x & 63, wid = threadIdx.x >> 6;
  const int wr = (wid >> 1) * 16, wc = (wid & 1) * 64;
#pragma unroll
  for (int ni = 0; ni < 4; ++ni)
#pragma unroll
    for (int r = 0; r < 4; ++r) {
      long m = rowBase + wr + ((lane >> 4) << 2) + r;
      int n = wc + ni * 16 + (lane & 15);
      out[m * HH + n] = acc[0][ni][r] * invnw[m] + gcb[n];
    }
}

extern "C" void kernel_launch(void* const* d_in, const int* in_sizes, int n_in,
                              void* d_out, int out_size, void* d_ws, size_t ws_size,
                              hipStream_t stream) {
  const float* x1  = (const float*)d_in[0];
  const float* w1  = (const float*)d_in[1];
  const float* w2  = (const float*)d_in[2];
  const float* gcw = (const float*)d_in[3];
  const float* gcb = (const float*)d_in[4];
  float* out = (float*)d_out;

  char* ws = (char*)d_ws;
  size_t off = 0;
  auto alloc = [&](size_t bytes) -> char* {
    char* p = ws + off;
    off += (bytes + 255) & ~(size_t)255;
    return p;
  };
  short* x1b  = (short*)alloc((size_t)NN * DD * 2);
  short* w1t  = (short*)alloc((size_t)DD * DD * 2);
  short* w2t  = (short*)alloc((size_t)PP * DD * 2);
  short* gcwt = (short*)alloc((size_t)HH * DD * 2);
  short* Y    = (short*)alloc((size_t)NN * DD * 2);
  short* xp   = (short*)alloc((size_t)NN * PP * 2);
  short* hT   = (short*)alloc((size_t)NN * HH * 2);
  float* invnw = (float*)alloc((size_t)NN * 4);
  float* Gp   = (float*)alloc((size_t)256 * PP * HH * 4);
  short* GT   = (short*)alloc((size_t)PP * HH * 2);

  hipLaunchKernelGGL(k_prep, dim3(4192), dim3(256), 0, stream,
                     x1, w1, w2, gcw, x1b, w1t, w2t, gcwt);
  hipLaunchKernelGGL(k_g13, dim3(640), dim3(256), 0, stream, x1b, w1t, gcwt, Y, hT);
  hipLaunchKernelGGL(k_g2e, dim3(256), dim3(256), 0, stream, Y, w2t, hT, xp, invnw, Gp);
  hipLaunchKernelGGL(k_red, dim3(128), dim3(128), 0, stream, Gp, GT);
  hipLaunchKernelGGL(k_gf, dim3(256), dim3(256), 0, stream, xp, GT, invnw, gcb, out);
}

// Round 16
// 48.994 us; speedup vs baseline: 1.3955x; 1.0818x over previous
//
#include <hip/hip_runtime.h>
#include <stdint.h>
#include <stddef.h>

typedef short s16x4 __attribute__((ext_vector_type(4)));
typedef short s16x8 __attribute__((ext_vector_type(8)));
typedef float f32x4 __attribute__((ext_vector_type(4)));

#define NN 8192
#define DD 512
#define PP 128
#define HH 128

// round-to-nearest-even f32 -> bf16 (bits in a short)
__device__ __forceinline__ short f2bf(float f) {
  unsigned u = __builtin_bit_cast(unsigned, f);
  u = (u + 0x7fffu + ((u >> 16) & 1u)) >> 16;
  return (short)u;
}

// async global->LDS, 16B per lane. LDS dest is wave-uniform base; HW adds lane*16.
__device__ __forceinline__ void async16(const void* g, void* l) {
  __builtin_amdgcn_global_load_lds(
      (const __attribute__((address_space(1))) unsigned int*)g,
      (__attribute__((address_space(3))) unsigned int*)l, 16, 0, 0);
}

// ---- 2-phase double-buffered (MF*32) x 128 bf16 GEMM core. 256 threads = 4 waves 2x2. ----
// A: [.][lda] row-major (K contiguous). BT: [.][ldb] row-major = B^T (K contiguous).
template <int MF>
__device__ __forceinline__ void gemm_core2(
    const short* __restrict__ A, long lda,
    const short* __restrict__ BT, long ldb,
    long rowBase, long colBase, int k0, int k1,
    short* As0, short* Bs0, short* As1, short* Bs1,
    f32x4 (*acc)[4]) {
  const int tid  = threadIdx.x;
  const int lane = tid & 63;
  const int wid  = tid >> 6;
  const int wr   = (wid >> 1) * (MF * 16);
  const int wc   = (wid & 1) * 64;
  const int srow = lane >> 3;
  const int skk  = (lane & 7) * 8;

#define STAGE_(AS, BS, KK)                                                    \
  do {                                                                        \
    _Pragma("unroll")                                                         \
    for (int it = 0; it < MF; ++it) {                                         \
      int r = wid * (MF * 8) + it * 8;                                        \
      async16(A + (rowBase + r + srow) * lda + (KK) + skk, (AS) + r * 64);    \
    }                                                                         \
    _Pragma("unroll")                                                         \
    for (int it = 0; it < 4; ++it) {                                          \
      int r = wid * 32 + it * 8;                                              \
      async16(BT + (colBase + r + srow) * ldb + (KK) + skk, (BS) + r * 64);   \
    }                                                                         \
  } while (0)

  STAGE_(As0, Bs0, k0);
  __syncthreads();
  for (int k = k0; k < k1; k += 64) {
    if (k + 64 < k1) STAGE_(As1, Bs1, k + 64);
#pragma unroll
    for (int ks = 0; ks < 64; ks += 32) {
      s16x8 af[MF], bfv[4];
#pragma unroll
      for (int i = 0; i < MF; ++i)
        af[i]  = *(const s16x8*)(As0 + (wr + i * 16 + (lane & 15)) * 64 + ks + (lane >> 4) * 8);
#pragma unroll
      for (int i = 0; i < 4; ++i)
        bfv[i] = *(const s16x8*)(Bs0 + (wc + i * 16 + (lane & 15)) * 64 + ks + (lane >> 4) * 8);
#pragma unroll
      for (int mi = 0; mi < MF; ++mi)
#pragma unroll
        for (int ni = 0; ni < 4; ++ni)
          acc[mi][ni] = __builtin_amdgcn_mfma_f32_16x16x32_bf16(af[mi], bfv[ni], acc[mi][ni], 0, 0, 0);
    }
    __syncthreads();
    short* t0 = As0; As0 = As1; As1 = t0;
    short* t1 = Bs0; Bs0 = Bs1; Bs1 = t1;
  }
#undef STAGE_
}

__device__ __forceinline__ void zero_acc2(f32x4 (*acc)[4], int mf) {
  f32x4 z = {0.f, 0.f, 0.f, 0.f};
  for (int i = 0; i < mf; ++i)
    for (int j = 0; j < 4; ++j) acc[i][j] = z;
}

// ---------------- prep: x1 fp32->bf16 (coalesced) + weights via LDS-tile transpose ----------------
// grid 4192: [0,4096) x1; [4096,4160) w1 (8x8 tiles of 64x64); [4160,4176) w2; [4176,4192) gcw.
__global__ __launch_bounds__(256) void k_prep(
    const float* __restrict__ x1, const float* __restrict__ w1,
    const float* __restrict__ w2, const float* __restrict__ gcw,
    short* __restrict__ x1b, short* __restrict__ w1t,
    short* __restrict__ w2t, short* __restrict__ gcwt) {
  __shared__ float tile[64][65];
  long b = blockIdx.x;
  int t = threadIdx.x;
  if (b < 4096) {                       // x1: 4M floats, 4 per thread, coalesced
    long i = b * 256 + t;
    float4 v = ((const float4*)x1)[i];
    s16x4 o;
    o[0] = f2bf(v.x); o[1] = f2bf(v.y); o[2] = f2bf(v.z); o[3] = f2bf(v.w);
    *(s16x4*)(x1b + i * 4) = o;
    return;
  }
  int bb = (int)(b - 4096);
  const float* src; short* dst; int K0, N0, ldn;
  if (bb < 64)      { src = w1;  dst = w1t;  ldn = 512; K0 = (bb >> 3) * 64; N0 = (bb & 7) * 64; }
  else if (bb < 80) { int c = bb - 64; src = w2;  dst = w2t;  ldn = 128; K0 = (c >> 1) * 64; N0 = (c & 1) * 64; }
  else              { int c = bb - 80; src = gcw; dst = gcwt; ldn = 128; K0 = (c >> 1) * 64; N0 = (c & 1) * 64; }
#pragma unroll
  for (int i = 0; i < 4; ++i) {
    int idx = i * 1024 + t * 4;            // coalesced float4 reads of src rows
    int row = idx >> 6, col = idx & 63;
    float4 v = *(const float4*)(src + (long)(K0 + row) * ldn + N0 + col);
    tile[row][col] = v.x; tile[row][col + 1] = v.y;
    tile[row][col + 2] = v.z; tile[row][col + 3] = v.w;
  }
  __syncthreads();
#pragma unroll
  for (int i = 0; i < 4; ++i) {
    int idx = i * 1024 + t * 4;
    int n = idx >> 6, k = idx & 63;        // dst[n][k] = src[k][n]
    s16x4 o;
#pragma unroll
    for (int u = 0; u < 4; ++u) o[u] = f2bf(tile[k + u][n]);
    *(s16x4*)(dst + (long)(N0 + n) * DD + K0 + k) = o;
  }
}

// ---------------- merged GEMM1 (relu(x1@W1)) + GEMM3 (h^T = (x1@gc_w)^T) ----------------
// blocks [0,512): g1 tiles 64x128.  blocks [512,640): g3 tiles 64x128 -> hT.  (verbatim R8)
__global__ __launch_bounds__(256) void k_g13(const short* __restrict__ x1b,
                                             const short* __restrict__ w1t,
                                             const short* __restrict__ gcwt,
                                             short* __restrict__ Y,
                                             short* __restrict__ hT) {
  __shared__ __align__(16) char smem[49152];
  short* As0 = (short*)smem;                    // 8KB  (64x64)
  short* As1 = (short*)(smem + 8192);           // 8KB
  short* Bs0 = (short*)(smem + 16384);          // 16KB (128x64)
  short* Bs1 = (short*)(smem + 32768);          // 16KB
  f32x4 acc[2][4];
  zero_acc2(acc, 2);
  const int bx = blockIdx.x;
  const int lane = threadIdx.x & 63, wid = threadIdx.x >> 6;
  const int wr = (wid >> 1) * 32, wc = (wid & 1) * 64;
  if (bx < 512) {
    long rowBase = (long)(bx >> 2) * 64;
    long colBase = (long)(bx & 3) * 128;
    gemm_core2<2>(x1b, DD, w1t, DD, rowBase, colBase, 0, DD, As0, Bs0, As1, Bs1, acc);
#pragma unroll
    for (int mi = 0; mi < 2; ++mi)
#pragma unroll
      for (int ni = 0; ni < 4; ++ni)
#pragma unroll
        for (int r = 0; r < 4; ++r) {
          long m = rowBase + wr + mi * 16 + ((lane >> 4) << 2) + r;
          long n = colBase + wc + ni * 16 + (lane & 15);
          float v = acc[mi][ni][r];
          Y[m * DD + n] = f2bf(v > 0.f ? v : 0.f);
        }
  } else {
    long rowBase = (long)(bx - 512) * 64;
    gemm_core2<2>(x1b, DD, gcwt, DD, rowBase, 0, 0, DD, As0, Bs0, As1, Bs1, acc);
    // transpose through LDS for coalesced hT writes (overlay staging; k-loop's
    // trailing barrier separates the last reads from these writes)
    short (*hs)[66] = (short(*)[66])smem;       // 128x66x2 = 16.9KB
#pragma unroll
    for (int mi = 0; mi < 2; ++mi)
#pragma unroll
      for (int ni = 0; ni < 4; ++ni)
#pragma unroll
        for (int r = 0; r < 4; ++r) {
          int m = wr + mi * 16 + ((lane >> 4) << 2) + r;
          int n = wc + ni * 16 + (lane & 15);
          hs[n][m] = f2bf(acc[mi][ni][r]);
        }
    __syncthreads();
    int t = threadIdx.x;
    int h = t >> 1, m0 = (t & 1) * 32;
#pragma unroll
    for (int j0 = 0; j0 < 32; j0 += 8) {
      s16x8 o;
#pragma unroll
      for (int u = 0; u < 8; ++u) o[u] = hs[h][m0 + j0 + u];
      *(s16x8*)(hT + (long)h * NN + rowBase + m0 + j0) = o;
    }
  }
}

// ------- fused GEMM2 + split-K G-chunk: per 64-row block (verbatim R8) ------------------------
__global__ __launch_bounds__(256) void k_g2e(const short* __restrict__ Y,
                                             const short* __restrict__ w2t,
                                             const short* __restrict__ hT,
                                             short* __restrict__ xp,
                                             float* __restrict__ invnw,
                                             float* __restrict__ Gp) {
  __shared__ __align__(16) char smem[50176];
  short* As0 = (short*)smem;                 // staging: [0, 49152)
  short* As1 = (short*)(smem + 8192);
  short* Bs0 = (short*)(smem + 16384);
  short* Bs1 = (short*)(smem + 32768);
  f32x4 acc[2][4];
  zero_acc2(acc, 2);
  const long rowBase = (long)blockIdx.x * 64;
  gemm_core2<2>(Y, DD, w2t, DD, rowBase, 0, 0, DD, As0, Bs0, As1, Bs1, acc);
  const int t = threadIdx.x;
  const int lane = t & 63, wid = t >> 6;
  {
    const int wr = (wid >> 1) * 32, wc = (wid & 1) * 64;
    float (*xs)[129] = (float(*)[129])smem;         // [0, 33024)
    float* invw_s = (float*)(smem + 49920);         // [49920, 50176)
    short* xpt_s = (short*)(smem + 33536);          // [33536, 49920)  [128p][64n]
#pragma unroll
    for (int mi = 0; mi < 2; ++mi)
#pragma unroll
      for (int ni = 0; ni < 4; ++ni)
#pragma unroll
        for (int r = 0; r < 4; ++r)
          xs[wr + mi * 16 + ((lane >> 4) << 2) + r][wc + ni * 16 + (lane & 15)] = acc[mi][ni][r];
    __syncthreads();
    if (t < 64) {  // fp32 row norm over P=128
      float s = 0.f;
#pragma unroll 8
      for (int i = 0; i < 128; ++i) { int c = (t + i) & 127; float v = xs[t][c]; s += v * v; }
      float nr = sqrtf(s);
      invnw[rowBase + t] = 1.f / (8192.f * nr);
      invw_s[t] = 1.f / nr;
    }
    __syncthreads();
    // xp [N][P] coalesced global write
#pragma unroll
    for (int i = 0; i < 4; ++i) {
      int seg = i * 256 + t;
      int r = seg >> 4, c0 = (seg & 15) * 8;
      s16x8 o;
#pragma unroll
      for (int u = 0; u < 8; ++u) o[u] = f2bf(xs[r][c0 + u]);
      *(s16x8*)(xp + (long)(rowBase + r) * PP + c0) = o;
    }
    // xpt_s[p][n] = xs[n][p] / w[n]  (LDS only — no global xpT)
    int c = t >> 1, n0 = (t & 1) * 32;
#pragma unroll
    for (int j0 = 0; j0 < 32; j0 += 8) {
      s16x8 o;
#pragma unroll
      for (int u = 0; u < 8; ++u) {
        int n = n0 + j0 + u;
        o[u] = f2bf(xs[n][c] * invw_s[n]);
      }
      *(s16x8*)(xpt_s + c * 64 + n0 + j0) = o;
    }
  }
  __syncthreads();
  // stage hT tile [128h][64n] into [0,16384) (xs dead now)
  {
    short* hts = (short*)smem;
    const int srow = lane >> 3, skk = (lane & 7) * 8;
#pragma unroll
    for (int it = 0; it < 4; ++it) {
      int r = wid * 32 + it * 8;
      async16(hT + (long)(r + srow) * NN + rowBase + skk, hts + r * 64);
    }
  }
  __syncthreads();
  // Gp[bid] = xpt_s[128x64] @ hts^T-form  (m=p, n=h, k=64 -> 2 ks-steps)
  {
    const short* xpt_s = (const short*)(smem + 33536);
    const short* hts = (const short*)smem;
    const int wr = (wid >> 1) * 64, wc = (wid & 1) * 64;
    f32x4 acc2[4][4];
    zero_acc2(acc2, 4);
#pragma unroll
    for (int ks = 0; ks < 64; ks += 32) {
      s16x8 af[4], bfv[4];
#pragma unroll
      for (int i = 0; i < 4; ++i)
        af[i]  = *(const s16x8*)(xpt_s + (wr + i * 16 + (lane & 15)) * 64 + ks + (lane >> 4) * 8);
#pragma unroll
      for (int i = 0; i < 4; ++i)
        bfv[i] = *(const s16x8*)(hts + (wc + i * 16 + (lane & 15)) * 64 + ks + (lane >> 4) * 8);
#pragma unroll
      for (int mi = 0; mi < 4; ++mi)
#pragma unroll
        for (int ni = 0; ni < 4; ++ni)
          acc2[mi][ni] = __builtin_amdgcn_mfma_f32_16x16x32_bf16(af[mi], bfv[ni], acc2[mi][ni], 0, 0, 0);
    }
    float* gp = Gp + (long)blockIdx.x * (PP * HH);
#pragma unroll
    for (int mi = 0; mi < 4; ++mi)
#pragma unroll
      for (int ni = 0; ni < 4; ++ni)
#pragma unroll
        for (int r = 0; r < 4; ++r) {
          int m = wr + mi * 16 + ((lane >> 4) << 2) + r;
          int n = wc + ni * 16 + (lane & 15);
          gp[m * HH + n] = acc2[mi][ni][r];
        }
  }
}

// ---------------- reduce partials -> G^T bf16 [H][P] (verbatim R8) ----------------
__global__ __launch_bounds__(256) void k_red(const float* __restrict__ Gp,
                                             short* __restrict__ GT) {
  int i = blockIdx.x * 256 + threadIdx.x;  // i = p*128 + h
  float s = 0.f;
#pragma unroll 8
  for (int j = 0; j < 128; ++j) s += Gp[j * (PP * HH) + i];
  int p = i >> 7, h = i & 127;
  GT[h * PP + p] = f2bf(s);
}

// ---------------- final: out = (xp @ G) * invnw[row] + gc_b (verbatim R8) ----------------
__global__ __launch_bounds__(256) void k_gf(const short* __restrict__ xp,
                                            const short* __restrict__ GT,
                                            const float* __restrict__ invnw,
                                            const float* __restrict__ gcb,
                                            float* __restrict__ out) {
  __shared__ __align__(16) char smem[49152];
  short* As0 = (short*)smem;
  short* As1 = (short*)(smem + 8192);
  short* Bs0 = (short*)(smem + 16384);
  short* Bs1 = (short*)(smem + 32768);
  f32x4 acc[2][4];
  zero_acc2(acc, 2);
  long rowBase = (long)blockIdx.x * 64;
  gemm_core2<2>(xp, PP, GT, PP, rowBase, 0, 0, PP, As0, Bs0, As1, Bs1, acc);
  const int lane = threadIdx.x & 63, wid = threadIdx.x >> 6;
  const int wr = (wid >> 1) * 32, wc = (wid & 1) * 64;
#pragma unroll
  for (int mi = 0; mi < 2; ++mi)
#pragma unroll
    for (int ni = 0; ni < 4; ++ni)
#pragma unroll
      for (int r = 0; r < 4; ++r) {
        long m = rowBase + wr + mi * 16 + ((lane >> 4) << 2) + r;
        int n = wc + ni * 16 + (lane & 15);
        out[m * HH + n] = acc[mi][ni][r] * invnw[m] + gcb[n];
      }
}

extern "C" void kernel_launch(void* const* d_in, const int* in_sizes, int n_in,
                              void* d_out, int out_size, void* d_ws, size_t ws_size,
                              hipStream_t stream) {
  const float* x1  = (const float*)d_in[0];
  const float* w1  = (const float*)d_in[1];
  const float* w2  = (const float*)d_in[2];
  const float* gcw = (const float*)d_in[3];
  const float* gcb = (const float*)d_in[4];
  float* out = (float*)d_out;

  char* ws = (char*)d_ws;
  size_t off = 0;
  auto alloc = [&](size_t bytes) -> char* {
    char* p = ws + off;
    off += (bytes + 255) & ~(size_t)255;
    return p;
  };
  short* x1b  = (short*)alloc((size_t)NN * DD * 2);
  short* w1t  = (short*)alloc((size_t)DD * DD * 2);
  short* w2t  = (short*)alloc((size_t)PP * DD * 2);
  short* gcwt = (short*)alloc((size_t)HH * DD * 2);
  short* Y    = (short*)alloc((size_t)NN * DD * 2);
  short* xp   = (short*)alloc((size_t)NN * PP * 2);
  short* hT   = (short*)alloc((size_t)NN * HH * 2);
  float* invnw = (float*)alloc((size_t)NN * 4);
  float* Gp   = (float*)alloc((size_t)128 * PP * HH * 4);
  short* GT   = (short*)alloc((size_t)PP * HH * 2);

  hipLaunchKernelGGL(k_prep, dim3(4192), dim3(256), 0, stream,
                     x1, w1, w2, gcw, x1b, w1t, w2t, gcwt);
  hipLaunchKernelGGL(k_g13, dim3(640), dim3(256), 0, stream, x1b, w1t, gcwt, Y, hT);
  hipLaunchKernelGGL(k_g2e, dim3(128), dim3(256), 0, stream, Y, w2t, hT, xp, invnw, Gp);
  hipLaunchKernelGGL(k_red, dim3(64), dim3(256), 0, stream, Gp, GT);
  hipLaunchKernelGGL(k_gf, dim3(128), dim3(256), 0, stream, xp, GT, invnw, gcb, out);
}

// Round 17
// 47.739 us; speedup vs baseline: 1.4322x; 1.0263x over previous
//
#include <hip/hip_runtime.h>
#include <stdint.h>
#include <stddef.h>

typedef short s16x4 __attribute__((ext_vector_type(4)));
typedef short s16x8 __attribute__((ext_vector_type(8)));
typedef float f32x4 __attribute__((ext_vector_type(4)));

#define NN 8192
#define DD 512
#define PP 128
#define HH 128

// round-to-nearest-even f32 -> bf16 (bits in a short)
__device__ __forceinline__ short f2bf(float f) {
  unsigned u = __builtin_bit_cast(unsigned, f);
  u = (u + 0x7fffu + ((u >> 16) & 1u)) >> 16;
  return (short)u;
}

// async global->LDS, 16B per lane. LDS dest is wave-uniform base; HW adds lane*16.
__device__ __forceinline__ void async16(const void* g, void* l) {
  __builtin_amdgcn_global_load_lds(
      (const __attribute__((address_space(1))) unsigned int*)g,
      (__attribute__((address_space(3))) unsigned int*)l, 16, 0, 0);
}

// ---- 2-phase double-buffered (MF*32) x 128 bf16 GEMM core. 256 threads = 4 waves 2x2. ----
// A: [.][lda] row-major (K contiguous). BT: [.][ldb] row-major = B^T (K contiguous).
template <int MF>
__device__ __forceinline__ void gemm_core2(
    const short* __restrict__ A, long lda,
    const short* __restrict__ BT, long ldb,
    long rowBase, long colBase, int k0, int k1,
    short* As0, short* Bs0, short* As1, short* Bs1,
    f32x4 (*acc)[4]) {
  const int tid  = threadIdx.x;
  const int lane = tid & 63;
  const int wid  = tid >> 6;
  const int wr   = (wid >> 1) * (MF * 16);
  const int wc   = (wid & 1) * 64;
  const int srow = lane >> 3;
  const int skk  = (lane & 7) * 8;

#define STAGE_(AS, BS, KK)                                                    \
  do {                                                                        \
    _Pragma("unroll")                                                         \
    for (int it = 0; it < MF; ++it) {                                         \
      int r = wid * (MF * 8) + it * 8;                                        \
      async16(A + (rowBase + r + srow) * lda + (KK) + skk, (AS) + r * 64);    \
    }                                                                         \
    _Pragma("unroll")                                                         \
    for (int it = 0; it < 4; ++it) {                                          \
      int r = wid * 32 + it * 8;                                              \
      async16(BT + (colBase + r + srow) * ldb + (KK) + skk, (BS) + r * 64);   \
    }                                                                         \
  } while (0)

  STAGE_(As0, Bs0, k0);
  __syncthreads();
  for (int k = k0; k < k1; k += 64) {
    if (k + 64 < k1) STAGE_(As1, Bs1, k + 64);
#pragma unroll
    for (int ks = 0; ks < 64; ks += 32) {
      s16x8 af[MF], bfv[4];
#pragma unroll
      for (int i = 0; i < MF; ++i)
        af[i]  = *(const s16x8*)(As0 + (wr + i * 16 + (lane & 15)) * 64 + ks + (lane >> 4) * 8);
#pragma unroll
      for (int i = 0; i < 4; ++i)
        bfv[i] = *(const s16x8*)(Bs0 + (wc + i * 16 + (lane & 15)) * 64 + ks + (lane >> 4) * 8);
#pragma unroll
      for (int mi = 0; mi < MF; ++mi)
#pragma unroll
        for (int ni = 0; ni < 4; ++ni)
          acc[mi][ni] = __builtin_amdgcn_mfma_f32_16x16x32_bf16(af[mi], bfv[ni], acc[mi][ni], 0, 0, 0);
    }
    __syncthreads();
    short* t0 = As0; As0 = As1; As1 = t0;
    short* t1 = Bs0; Bs0 = Bs1; Bs1 = t1;
  }
#undef STAGE_
}

__device__ __forceinline__ void zero_acc2(f32x4 (*acc)[4], int mf) {
  f32x4 z = {0.f, 0.f, 0.f, 0.f};
  for (int i = 0; i < mf; ++i)
    for (int j = 0; j < 4; ++j) acc[i][j] = z;
}

// ---------------- prep: x1 fp32->bf16 (coalesced) + weights via LDS-tile transpose ----------------
// grid 4192: [0,4096) x1; [4096,4160) w1 (8x8 tiles of 64x64); [4160,4176) w2; [4176,4192) gcw.
__global__ __launch_bounds__(256) void k_prep(
    const float* __restrict__ x1, const float* __restrict__ w1,
    const float* __restrict__ w2, const float* __restrict__ gcw,
    short* __restrict__ x1b, short* __restrict__ w1t,
    short* __restrict__ w2t, short* __restrict__ gcwt) {
  __shared__ float tile[64][65];
  long b = blockIdx.x;
  int t = threadIdx.x;
  if (b < 4096) {                       // x1: 4M floats, 4 per thread, coalesced
    long i = b * 256 + t;
    float4 v = ((const float4*)x1)[i];
    s16x4 o;
    o[0] = f2bf(v.x); o[1] = f2bf(v.y); o[2] = f2bf(v.z); o[3] = f2bf(v.w);
    *(s16x4*)(x1b + i * 4) = o;
    return;
  }
  int bb = (int)(b - 4096);
  const float* src; short* dst; int K0, N0, ldn;
  if (bb < 64)      { src = w1;  dst = w1t;  ldn = 512; K0 = (bb >> 3) * 64; N0 = (bb & 7) * 64; }
  else if (bb < 80) { int c = bb - 64; src = w2;  dst = w2t;  ldn = 128; K0 = (c >> 1) * 64; N0 = (c & 1) * 64; }
  else              { int c = bb - 80; src = gcw; dst = gcwt; ldn = 128; K0 = (c >> 1) * 64; N0 = (c & 1) * 64; }
#pragma unroll
  for (int i = 0; i < 4; ++i) {
    int idx = i * 1024 + t * 4;            // coalesced float4 reads of src rows
    int row = idx >> 6, col = idx & 63;
    float4 v = *(const float4*)(src + (long)(K0 + row) * ldn + N0 + col);
    tile[row][col] = v.x; tile[row][col + 1] = v.y;
    tile[row][col + 2] = v.z; tile[row][col + 3] = v.w;
  }
  __syncthreads();
#pragma unroll
  for (int i = 0; i < 4; ++i) {
    int idx = i * 1024 + t * 4;
    int n = idx >> 6, k = idx & 63;        // dst[n][k] = src[k][n]
    s16x4 o;
#pragma unroll
    for (int u = 0; u < 4; ++u) o[u] = f2bf(tile[k + u][n]);
    *(s16x4*)(dst + (long)(N0 + n) * DD + K0 + k) = o;
  }
}

// ---------------- merged GEMM1 (relu(x1@W1)) + GEMM3 (h^T = (x1@gc_w)^T) ----------------
// grid 768 = exactly 3 blocks/CU (48KB LDS): balanced makespan (2 g1 + 1 half-cost g3 per CU).
// blocks [0,512): g1 tiles 64x128.  blocks [512,768): g3 tiles 32x128 -> hT (MF=1 core).
__global__ __launch_bounds__(256) void k_g13(const short* __restrict__ x1b,
                                             const short* __restrict__ w1t,
                                             const short* __restrict__ gcwt,
                                             short* __restrict__ Y,
                                             short* __restrict__ hT) {
  __shared__ __align__(16) char smem[49152];
  short* As0 = (short*)smem;                    // 8KB slot (MF=2) / 4KB used (MF=1)
  short* As1 = (short*)(smem + 8192);
  short* Bs0 = (short*)(smem + 16384);          // 16KB (128x64)
  short* Bs1 = (short*)(smem + 32768);          // 16KB
  const int bx = blockIdx.x;
  const int lane = threadIdx.x & 63, wid = threadIdx.x >> 6;
  if (bx < 512) {
    f32x4 acc[2][4];
    zero_acc2(acc, 2);
    const int wr = (wid >> 1) * 32, wc = (wid & 1) * 64;
    long rowBase = (long)(bx >> 2) * 64;
    long colBase = (long)(bx & 3) * 128;
    gemm_core2<2>(x1b, DD, w1t, DD, rowBase, colBase, 0, DD, As0, Bs0, As1, Bs1, acc);
#pragma unroll
    for (int mi = 0; mi < 2; ++mi)
#pragma unroll
      for (int ni = 0; ni < 4; ++ni)
#pragma unroll
        for (int r = 0; r < 4; ++r) {
          long m = rowBase + wr + mi * 16 + ((lane >> 4) << 2) + r;
          long n = colBase + wc + ni * 16 + (lane & 15);
          float v = acc[mi][ni][r];
          Y[m * DD + n] = f2bf(v > 0.f ? v : 0.f);
        }
  } else {
    f32x4 acc[1][4];
    zero_acc2(acc, 1);
    const int wr = (wid >> 1) * 16, wc = (wid & 1) * 64;
    long rowBase = (long)(bx - 512) * 32;
    gemm_core2<1>(x1b, DD, gcwt, DD, rowBase, 0, 0, DD, As0, Bs0, As1, Bs1, acc);
    // transpose through LDS for coalesced hT writes (overlay staging; k-loop's
    // trailing barrier separates the last reads from these writes)
    short (*hs)[34] = (short(*)[34])smem;       // 128x34x2 = 8.7KB
#pragma unroll
    for (int ni = 0; ni < 4; ++ni)
#pragma unroll
      for (int r = 0; r < 4; ++r) {
        int m = wr + ((lane >> 4) << 2) + r;
        int n = wc + ni * 16 + (lane & 15);
        hs[n][m] = f2bf(acc[0][ni][r]);
      }
    __syncthreads();
    int t = threadIdx.x;
    int h = t >> 1, m0 = (t & 1) * 16;
#pragma unroll
    for (int j0 = 0; j0 < 16; j0 += 8) {
      s16x8 o;
#pragma unroll
      for (int u = 0; u < 8; ++u) o[u] = hs[h][m0 + j0 + u];
      *(s16x8*)(hT + (long)h * NN + rowBase + m0 + j0) = o;
    }
  }
}

// ------- fused GEMM2 + split-K G-chunk: per 64-row block (verbatim R16) ------------------------
__global__ __launch_bounds__(256) void k_g2e(const short* __restrict__ Y,
                                             const short* __restrict__ w2t,
                                             const short* __restrict__ hT,
                                             short* __restrict__ xp,
                                             float* __restrict__ invnw,
                                             float* __restrict__ Gp) {
  __shared__ __align__(16) char smem[50176];
  short* As0 = (short*)smem;                 // staging: [0, 49152)
  short* As1 = (short*)(smem + 8192);
  short* Bs0 = (short*)(smem + 16384);
  short* Bs1 = (short*)(smem + 32768);
  f32x4 acc[2][4];
  zero_acc2(acc, 2);
  const long rowBase = (long)blockIdx.x * 64;
  gemm_core2<2>(Y, DD, w2t, DD, rowBase, 0, 0, DD, As0, Bs0, As1, Bs1, acc);
  const int t = threadIdx.x;
  const int lane = t & 63, wid = t >> 6;
  {
    const int wr = (wid >> 1) * 32, wc = (wid & 1) * 64;
    float (*xs)[129] = (float(*)[129])smem;         // [0, 33024)
    float* invw_s = (float*)(smem + 49920);         // [49920, 50176)
    short* xpt_s = (short*)(smem + 33536);          // [33536, 49920)  [128p][64n]
#pragma unroll
    for (int mi = 0; mi < 2; ++mi)
#pragma unroll
      for (int ni = 0; ni < 4; ++ni)
#pragma unroll
        for (int r = 0; r < 4; ++r)
          xs[wr + mi * 16 + ((lane >> 4) << 2) + r][wc + ni * 16 + (lane & 15)] = acc[mi][ni][r];
    __syncthreads();
    if (t < 64) {  // fp32 row norm over P=128
      float s = 0.f;
#pragma unroll 8
      for (int i = 0; i < 128; ++i) { int c = (t + i) & 127; float v = xs[t][c]; s += v * v; }
      float nr = sqrtf(s);
      invnw[rowBase + t] = 1.f / (8192.f * nr);
      invw_s[t] = 1.f / nr;
    }
    __syncthreads();
    // xp [N][P] coalesced global write
#pragma unroll
    for (int i = 0; i < 4; ++i) {
      int seg = i * 256 + t;
      int r = seg >> 4, c0 = (seg & 15) * 8;
      s16x8 o;
#pragma unroll
      for (int u = 0; u < 8; ++u) o[u] = f2bf(xs[r][c0 + u]);
      *(s16x8*)(xp + (long)(rowBase + r) * PP + c0) = o;
    }
    // xpt_s[p][n] = xs[n][p] / w[n]  (LDS only — no global xpT)
    int c = t >> 1, n0 = (t & 1) * 32;
#pragma unroll
    for (int j0 = 0; j0 < 32; j0 += 8) {
      s16x8 o;
#pragma unroll
      for (int u = 0; u < 8; ++u) {
        int n = n0 + j0 + u;
        o[u] = f2bf(xs[n][c] * invw_s[n]);
      }
      *(s16x8*)(xpt_s + c * 64 + n0 + j0) = o;
    }
  }
  __syncthreads();
  // stage hT tile [128h][64n] into [0,16384) (xs dead now)
  {
    short* hts = (short*)smem;
    const int srow = lane >> 3, skk = (lane & 7) * 8;
#pragma unroll
    for (int it = 0; it < 4; ++it) {
      int r = wid * 32 + it * 8;
      async16(hT + (long)(r + srow) * NN + rowBase + skk, hts + r * 64);
    }
  }
  __syncthreads();
  // Gp[bid] = xpt_s[128x64] @ hts^T-form  (m=p, n=h, k=64 -> 2 ks-steps)
  {
    const short* xpt_s = (const short*)(smem + 33536);
    const short* hts = (const short*)smem;
    const int wr = (wid >> 1) * 64, wc = (wid & 1) * 64;
    f32x4 acc2[4][4];
    zero_acc2(acc2, 4);
#pragma unroll
    for (int ks = 0; ks < 64; ks += 32) {
      s16x8 af[4], bfv[4];
#pragma unroll
      for (int i = 0; i < 4; ++i)
        af[i]  = *(const s16x8*)(xpt_s + (wr + i * 16 + (lane & 15)) * 64 + ks + (lane >> 4) * 8);
#pragma unroll
      for (int i = 0; i < 4; ++i)
        bfv[i] = *(const s16x8*)(hts + (wc + i * 16 + (lane & 15)) * 64 + ks + (lane >> 4) * 8);
#pragma unroll
      for (int mi = 0; mi < 4; ++mi)
#pragma unroll
        for (int ni = 0; ni < 4; ++ni)
          acc2[mi][ni] = __builtin_amdgcn_mfma_f32_16x16x32_bf16(af[mi], bfv[ni], acc2[mi][ni], 0, 0, 0);
    }
    float* gp = Gp + (long)blockIdx.x * (PP * HH);
#pragma unroll
    for (int mi = 0; mi < 4; ++mi)
#pragma unroll
      for (int ni = 0; ni < 4; ++ni)
#pragma unroll
        for (int r = 0; r < 4; ++r) {
          int m = wr + mi * 16 + ((lane >> 4) << 2) + r;
          int n = wc + ni * 16 + (lane & 15);
          gp[m * HH + n] = acc2[mi][ni][r];
        }
  }
}

// ---------------- reduce partials -> G^T bf16 [H][P] (verbatim R16) ----------------
__global__ __launch_bounds__(256) void k_red(const float* __restrict__ Gp,
                                             short* __restrict__ GT) {
  int i = blockIdx.x * 256 + threadIdx.x;  // i = p*128 + h
  float s = 0.f;
#pragma unroll 8
  for (int j = 0; j < 128; ++j) s += Gp[j * (PP * HH) + i];
  int p = i >> 7, h = i & 127;
  GT[h * PP + p] = f2bf(s);
}

// ---------------- final: out = (xp @ G) * invnw[row] + gc_b (verbatim R16) ----------------
__global__ __launch_bounds__(256) void k_gf(const short* __restrict__ xp,
                                            const short* __restrict__ GT,
                                            const float* __restrict__ invnw,
                                            const float* __restrict__ gcb,
                                            float* __restrict__ out) {
  __shared__ __align__(16) char smem[49152];
  short* As0 = (short*)smem;
  short* As1 = (short*)(smem + 8192);
  short* Bs0 = (short*)(smem + 16384);
  short* Bs1 = (short*)(smem + 32768);
  f32x4 acc[2][4];
  zero_acc2(acc, 2);
  long rowBase = (long)blockIdx.x * 64;
  gemm_core2<2>(xp, PP, GT, PP, rowBase, 0, 0, PP, As0, Bs0, As1, Bs1, acc);
  const int lane = threadIdx.x & 63, wid = threadIdx.x >> 6;
  const int wr = (wid >> 1) * 32, wc = (wid & 1) * 64;
#pragma unroll
  for (int mi = 0; mi < 2; ++mi)
#pragma unroll
    for (int ni = 0; ni < 4; ++ni)
#pragma unroll
      for (int r = 0; r < 4; ++r) {
        long m = rowBase + wr + mi * 16 + ((lane >> 4) << 2) + r;
        int n = wc + ni * 16 + (lane & 15);
        out[m * HH + n] = acc[mi][ni][r] * invnw[m] + gcb[n];
      }
}

extern "C" void kernel_launch(void* const* d_in, const int* in_sizes, int n_in,
                              void* d_out, int out_size, void* d_ws, size_t ws_size,
                              hipStream_t stream) {
  const float* x1  = (const float*)d_in[0];
  const float* w1  = (const float*)d_in[1];
  const float* w2  = (const float*)d_in[2];
  const float* gcw = (const float*)d_in[3];
  const float* gcb = (const float*)d_in[4];
  float* out = (float*)d_out;

  char* ws = (char*)d_ws;
  size_t off = 0;
  auto alloc = [&](size_t bytes) -> char* {
    char* p = ws + off;
    off += (bytes + 255) & ~(size_t)255;
    return p;
  };
  short* x1b  = (short*)alloc((size_t)NN * DD * 2);
  short* w1t  = (short*)alloc((size_t)DD * DD * 2);
  short* w2t  = (short*)alloc((size_t)PP * DD * 2);
  short* gcwt = (short*)alloc((size_t)HH * DD * 2);
  short* Y    = (short*)alloc((size_t)NN * DD * 2);
  short* xp   = (short*)alloc((size_t)NN * PP * 2);
  short* hT   = (short*)alloc((size_t)NN * HH * 2);
  float* invnw = (float*)alloc((size_t)NN * 4);
  float* Gp   = (float*)alloc((size_t)128 * PP * HH * 4);
  short* GT   = (short*)alloc((size_t)PP * HH * 2);

  hipLaunchKernelGGL(k_prep, dim3(4192), dim3(256), 0, stream,
                     x1, w1, w2, gcw, x1b, w1t, w2t, gcwt);
  hipLaunchKernelGGL(k_g13, dim3(768), dim3(256), 0, stream, x1b, w1t, gcwt, Y, hT);
  hipLaunchKernelGGL(k_g2e, dim3(128), dim3(256), 0, stream, Y, w2t, hT, xp, invnw, Gp);
  hipLaunchKernelGGL(k_red, dim3(64), dim3(256), 0, stream, Gp, GT);
  hipLaunchKernelGGL(k_gf, dim3(128), dim3(256), 0, stream, xp, GT, invnw, gcb, out);
}

// Round 18
// 47.065 us; speedup vs baseline: 1.4527x; 1.0143x over previous
//
#include <hip/hip_runtime.h>
#include <stdint.h>
#include <stddef.h>

typedef short s16x4 __attribute__((ext_vector_type(4)));
typedef short s16x8 __attribute__((ext_vector_type(8)));
typedef float f32x4 __attribute__((ext_vector_type(4)));

#define NN 8192
#define DD 512
#define PP 128
#define HH 128

// round-to-nearest-even f32 -> bf16 (bits in a short)
__device__ __forceinline__ short f2bf(float f) {
  unsigned u = __builtin_bit_cast(unsigned, f);
  u = (u + 0x7fffu + ((u >> 16) & 1u)) >> 16;
  return (short)u;
}

// async global->LDS, 16B per lane. LDS dest is wave-uniform base; HW adds lane*16.
__device__ __forceinline__ void async16(const void* g, void* l) {
  __builtin_amdgcn_global_load_lds(
      (const __attribute__((address_space(1))) unsigned int*)g,
      (__attribute__((address_space(3))) unsigned int*)l, 16, 0, 0);
}

// ---- 2-phase double-buffered (MF*32) x 128 bf16 GEMM core. 256 threads = 4 waves 2x2. ----
// A: [.][lda] row-major (K contiguous). BT: [.][ldb] row-major = B^T (K contiguous).
template <int MF>
__device__ __forceinline__ void gemm_core2(
    const short* __restrict__ A, long lda,
    const short* __restrict__ BT, long ldb,
    long rowBase, long colBase, int k0, int k1,
    short* As0, short* Bs0, short* As1, short* Bs1,
    f32x4 (*acc)[4]) {
  const int tid  = threadIdx.x;
  const int lane = tid & 63;
  const int wid  = tid >> 6;
  const int wr   = (wid >> 1) * (MF * 16);
  const int wc   = (wid & 1) * 64;
  const int srow = lane >> 3;
  const int skk  = (lane & 7) * 8;

#define STAGE_(AS, BS, KK)                                                    \
  do {                                                                        \
    _Pragma("unroll")                                                         \
    for (int it = 0; it < MF; ++it) {                                         \
      int r = wid * (MF * 8) + it * 8;                                        \
      async16(A + (rowBase + r + srow) * lda + (KK) + skk, (AS) + r * 64);    \
    }                                                                         \
    _Pragma("unroll")                                                         \
    for (int it = 0; it < 4; ++it) {                                          \
      int r = wid * 32 + it * 8;                                              \
      async16(BT + (colBase + r + srow) * ldb + (KK) + skk, (BS) + r * 64);   \
    }                                                                         \
  } while (0)

  STAGE_(As0, Bs0, k0);
  __syncthreads();
  for (int k = k0; k < k1; k += 64) {
    if (k + 64 < k1) STAGE_(As1, Bs1, k + 64);
#pragma unroll
    for (int ks = 0; ks < 64; ks += 32) {
      s16x8 af[MF], bfv[4];
#pragma unroll
      for (int i = 0; i < MF; ++i)
        af[i]  = *(const s16x8*)(As0 + (wr + i * 16 + (lane & 15)) * 64 + ks + (lane >> 4) * 8);
#pragma unroll
      for (int i = 0; i < 4; ++i)
        bfv[i] = *(const s16x8*)(Bs0 + (wc + i * 16 + (lane & 15)) * 64 + ks + (lane >> 4) * 8);
#pragma unroll
      for (int mi = 0; mi < MF; ++mi)
#pragma unroll
        for (int ni = 0; ni < 4; ++ni)
          acc[mi][ni] = __builtin_amdgcn_mfma_f32_16x16x32_bf16(af[mi], bfv[ni], acc[mi][ni], 0, 0, 0);
    }
    __syncthreads();
    short* t0 = As0; As0 = As1; As1 = t0;
    short* t1 = Bs0; Bs0 = Bs1; Bs1 = t1;
  }
#undef STAGE_
}

__device__ __forceinline__ void zero_acc2(f32x4 (*acc)[4], int mf) {
  f32x4 z = {0.f, 0.f, 0.f, 0.f};
  for (int i = 0; i < mf; ++i)
    for (int j = 0; j < 4; ++j) acc[i][j] = z;
}

// ---------------- prep: x1 fp32->bf16 (coalesced) + weights via LDS-tile transpose ----------------
// grid 4192: [0,4096) x1; [4096,4160) w1 (8x8 tiles of 64x64); [4160,4176) w2; [4176,4192) gcw.
__global__ __launch_bounds__(256) void k_prep(
    const float* __restrict__ x1, const float* __restrict__ w1,
    const float* __restrict__ w2, const float* __restrict__ gcw,
    short* __restrict__ x1b, short* __restrict__ w1t,
    short* __restrict__ w2t, short* __restrict__ gcwt) {
  __shared__ float tile[64][65];
  long b = blockIdx.x;
  int t = threadIdx.x;
  if (b < 4096) {                       // x1: 4M floats, 4 per thread, coalesced
    long i = b * 256 + t;
    float4 v = ((const float4*)x1)[i];
    s16x4 o;
    o[0] = f2bf(v.x); o[1] = f2bf(v.y); o[2] = f2bf(v.z); o[3] = f2bf(v.w);
    *(s16x4*)(x1b + i * 4) = o;
    return;
  }
  int bb = (int)(b - 4096);
  const float* src; short* dst; int K0, N0, ldn;
  if (bb < 64)      { src = w1;  dst = w1t;  ldn = 512; K0 = (bb >> 3) * 64; N0 = (bb & 7) * 64; }
  else if (bb < 80) { int c = bb - 64; src = w2;  dst = w2t;  ldn = 128; K0 = (c >> 1) * 64; N0 = (c & 1) * 64; }
  else              { int c = bb - 80; src = gcw; dst = gcwt; ldn = 128; K0 = (c >> 1) * 64; N0 = (c & 1) * 64; }
#pragma unroll
  for (int i = 0; i < 4; ++i) {
    int idx = i * 1024 + t * 4;            // coalesced float4 reads of src rows
    int row = idx >> 6, col = idx & 63;
    float4 v = *(const float4*)(src + (long)(K0 + row) * ldn + N0 + col);
    tile[row][col] = v.x; tile[row][col + 1] = v.y;
    tile[row][col + 2] = v.z; tile[row][col + 3] = v.w;
  }
  __syncthreads();
#pragma unroll
  for (int i = 0; i < 4; ++i) {
    int idx = i * 1024 + t * 4;
    int n = idx >> 6, k = idx & 63;        // dst[n][k] = src[k][n]
    s16x4 o;
#pragma unroll
    for (int u = 0; u < 4; ++u) o[u] = f2bf(tile[k + u][n]);
    *(s16x4*)(dst + (long)(N0 + n) * DD + K0 + k) = o;
  }
}

// ---------------- merged GEMM1 (relu(x1@W1)) + GEMM3 (h^T = (x1@gc_w)^T) ----------------
// grid 512 = exactly 2 blocks/CU (64KB LDS): each CU gets one 4-unit g1 block + one 1-unit g3.
// blocks [0,256): g1 tiles 128x128 (MF=4).  blocks [256,512): g3 tiles 32x128 -> hT (MF=1).
__global__ __launch_bounds__(256) void k_g13(const short* __restrict__ x1b,
                                             const short* __restrict__ w1t,
                                             const short* __restrict__ gcwt,
                                             short* __restrict__ Y,
                                             short* __restrict__ hT) {
  __shared__ __align__(16) char smem[65536];
  short* As0 = (short*)smem;                    // 16KB slot (MF=4) / 4KB used (MF=1)
  short* As1 = (short*)(smem + 16384);
  short* Bs0 = (short*)(smem + 32768);          // 16KB (128x64)
  short* Bs1 = (short*)(smem + 49152);
  const int bx = blockIdx.x;
  const int lane = threadIdx.x & 63, wid = threadIdx.x >> 6;
  if (bx < 256) {
    f32x4 acc[4][4];
    zero_acc2(acc, 4);
    const int wr = (wid >> 1) * 64, wc = (wid & 1) * 64;
    long rowBase = (long)(bx >> 2) * 128;
    long colBase = (long)(bx & 3) * 128;
    gemm_core2<4>(x1b, DD, w1t, DD, rowBase, colBase, 0, DD, As0, Bs0, As1, Bs1, acc);
#pragma unroll
    for (int mi = 0; mi < 4; ++mi)
#pragma unroll
      for (int ni = 0; ni < 4; ++ni)
#pragma unroll
        for (int r = 0; r < 4; ++r) {
          long m = rowBase + wr + mi * 16 + ((lane >> 4) << 2) + r;
          long n = colBase + wc + ni * 16 + (lane & 15);
          float v = acc[mi][ni][r];
          Y[m * DD + n] = f2bf(v > 0.f ? v : 0.f);
        }
  } else {
    f32x4 acc[1][4];
    zero_acc2(acc, 1);
    const int wr = (wid >> 1) * 16, wc = (wid & 1) * 64;
    long rowBase = (long)(bx - 256) * 32;
    gemm_core2<1>(x1b, DD, gcwt, DD, rowBase, 0, 0, DD, As0, Bs0, As1, Bs1, acc);
    // transpose through LDS for coalesced hT writes (overlay staging; k-loop's
    // trailing barrier separates the last reads from these writes)
    short (*hs)[34] = (short(*)[34])smem;       // 128x34x2 = 8.7KB
#pragma unroll
    for (int ni = 0; ni < 4; ++ni)
#pragma unroll
      for (int r = 0; r < 4; ++r) {
        int m = wr + ((lane >> 4) << 2) + r;
        int n = wc + ni * 16 + (lane & 15);
        hs[n][m] = f2bf(acc[0][ni][r]);
      }
    __syncthreads();
    int t = threadIdx.x;
    int h = t >> 1, m0 = (t & 1) * 16;
#pragma unroll
    for (int j0 = 0; j0 < 16; j0 += 8) {
      s16x8 o;
#pragma unroll
      for (int u = 0; u < 8; ++u) o[u] = hs[h][m0 + j0 + u];
      *(s16x8*)(hT + (long)h * NN + rowBase + m0 + j0) = o;
    }
  }
}

// ------- fused GEMM2 + split-K G-chunk: per 64-row block (verbatim R17) ------------------------
__global__ __launch_bounds__(256) void k_g2e(const short* __restrict__ Y,
                                             const short* __restrict__ w2t,
                                             const short* __restrict__ hT,
                                             short* __restrict__ xp,
                                             float* __restrict__ invnw,
                                             float* __restrict__ Gp) {
  __shared__ __align__(16) char smem[50176];
  short* As0 = (short*)smem;                 // staging: [0, 49152)
  short* As1 = (short*)(smem + 8192);
  short* Bs0 = (short*)(smem + 16384);
  short* Bs1 = (short*)(smem + 32768);
  f32x4 acc[2][4];
  zero_acc2(acc, 2);
  const long rowBase = (long)blockIdx.x * 64;
  gemm_core2<2>(Y, DD, w2t, DD, rowBase, 0, 0, DD, As0, Bs0, As1, Bs1, acc);
  const int t = threadIdx.x;
  const int lane = t & 63, wid = t >> 6;
  {
    const int wr = (wid >> 1) * 32, wc = (wid & 1) * 64;
    float (*xs)[129] = (float(*)[129])smem;         // [0, 33024)
    float* invw_s = (float*)(smem + 49920);         // [49920, 50176)
    short* xpt_s = (short*)(smem + 33536);          // [33536, 49920)  [128p][64n]
#pragma unroll
    for (int mi = 0; mi < 2; ++mi)
#pragma unroll
      for (int ni = 0; ni < 4; ++ni)
#pragma unroll
        for (int r = 0; r < 4; ++r)
          xs[wr + mi * 16 + ((lane >> 4) << 2) + r][wc + ni * 16 + (lane & 15)] = acc[mi][ni][r];
    __syncthreads();
    if (t < 64) {  // fp32 row norm over P=128
      float s = 0.f;
#pragma unroll 8
      for (int i = 0; i < 128; ++i) { int c = (t + i) & 127; float v = xs[t][c]; s += v * v; }
      float nr = sqrtf(s);
      invnw[rowBase + t] = 1.f / (8192.f * nr);
      invw_s[t] = 1.f / nr;
    }
    __syncthreads();
    // xp [N][P] coalesced global write
#pragma unroll
    for (int i = 0; i < 4; ++i) {
      int seg = i * 256 + t;
      int r = seg >> 4, c0 = (seg & 15) * 8;
      s16x8 o;
#pragma unroll
      for (int u = 0; u < 8; ++u) o[u] = f2bf(xs[r][c0 + u]);
      *(s16x8*)(xp + (long)(rowBase + r) * PP + c0) = o;
    }
    // xpt_s[p][n] = xs[n][p] / w[n]  (LDS only — no global xpT)
    int c = t >> 1, n0 = (t & 1) * 32;
#pragma unroll
    for (int j0 = 0; j0 < 32; j0 += 8) {
      s16x8 o;
#pragma unroll
      for (int u = 0; u < 8; ++u) {
        int n = n0 + j0 + u;
        o[u] = f2bf(xs[n][c] * invw_s[n]);
      }
      *(s16x8*)(xpt_s + c * 64 + n0 + j0) = o;
    }
  }
  __syncthreads();
  // stage hT tile [128h][64n] into [0,16384) (xs dead now)
  {
    short* hts = (short*)smem;
    const int srow = lane >> 3, skk = (lane & 7) * 8;
#pragma unroll
    for (int it = 0; it < 4; ++it) {
      int r = wid * 32 + it * 8;
      async16(hT + (long)(r + srow) * NN + rowBase + skk, hts + r * 64);
    }
  }
  __syncthreads();
  // Gp[bid] = xpt_s[128x64] @ hts^T-form  (m=p, n=h, k=64 -> 2 ks-steps)
  {
    const short* xpt_s = (const short*)(smem + 33536);
    const short* hts = (const short*)smem;
    const int wr = (wid >> 1) * 64, wc = (wid & 1) * 64;
    f32x4 acc2[4][4];
    zero_acc2(acc2, 4);
#pragma unroll
    for (int ks = 0; ks < 64; ks += 32) {
      s16x8 af[4], bfv[4];
#pragma unroll
      for (int i = 0; i < 4; ++i)
        af[i]  = *(const s16x8*)(xpt_s + (wr + i * 16 + (lane & 15)) * 64 + ks + (lane >> 4) * 8);
#pragma unroll
      for (int i = 0; i < 4; ++i)
        bfv[i] = *(const s16x8*)(hts + (wc + i * 16 + (lane & 15)) * 64 + ks + (lane >> 4) * 8);
#pragma unroll
      for (int mi = 0; mi < 4; ++mi)
#pragma unroll
        for (int ni = 0; ni < 4; ++ni)
          acc2[mi][ni] = __builtin_amdgcn_mfma_f32_16x16x32_bf16(af[mi], bfv[ni], acc2[mi][ni], 0, 0, 0);
    }
    float* gp = Gp + (long)blockIdx.x * (PP * HH);
#pragma unroll
    for (int mi = 0; mi < 4; ++mi)
#pragma unroll
      for (int ni = 0; ni < 4; ++ni)
#pragma unroll
        for (int r = 0; r < 4; ++r) {
          int m = wr + mi * 16 + ((lane >> 4) << 2) + r;
          int n = wc + ni * 16 + (lane & 15);
          gp[m * HH + n] = acc2[mi][ni][r];
        }
  }
}

// ---------------- reduce partials -> G^T bf16 [H][P] (verbatim R17) ----------------
__global__ __launch_bounds__(256) void k_red(const float* __restrict__ Gp,
                                             short* __restrict__ GT) {
  int i = blockIdx.x * 256 + threadIdx.x;  // i = p*128 + h
  float s = 0.f;
#pragma unroll 8
  for (int j = 0; j < 128; ++j) s += Gp[j * (PP * HH) + i];
  int p = i >> 7, h = i & 127;
  GT[h * PP + p] = f2bf(s);
}

// ---------------- final: out = (xp @ G) * invnw[row] + gc_b (verbatim R17) ----------------
__global__ __launch_bounds__(256) void k_gf(const short* __restrict__ xp,
                                            const short* __restrict__ GT,
                                            const float* __restrict__ invnw,
                                            const float* __restrict__ gcb,
                                            float* __restrict__ out) {
  __shared__ __align__(16) char smem[49152];
  short* As0 = (short*)smem;
  short* As1 = (short*)(smem + 8192);
  short* Bs0 = (short*)(smem + 16384);
  short* Bs1 = (short*)(smem + 32768);
  f32x4 acc[2][4];
  zero_acc2(acc, 2);
  long rowBase = (long)blockIdx.x * 64;
  gemm_core2<2>(xp, PP, GT, PP, rowBase, 0, 0, PP, As0, Bs0, As1, Bs1, acc);
  const int lane = threadIdx.x & 63, wid = threadIdx.x >> 6;
  const int wr = (wid >> 1) * 32, wc = (wid & 1) * 64;
#pragma unroll
  for (int mi = 0; mi < 2; ++mi)
#pragma unroll
    for (int ni = 0; ni < 4; ++ni)
#pragma unroll
      for (int r = 0; r < 4; ++r) {
        long m = rowBase + wr + mi * 16 + ((lane >> 4) << 2) + r;
        int n = wc + ni * 16 + (lane & 15);
        out[m * HH + n] = acc[mi][ni][r] * invnw[m] + gcb[n];
      }
}

extern "C" void kernel_launch(void* const* d_in, const int* in_sizes, int n_in,
                              void* d_out, int out_size, void* d_ws, size_t ws_size,
                              hipStream_t stream) {
  const float* x1  = (const float*)d_in[0];
  const float* w1  = (const float*)d_in[1];
  const float* w2  = (const float*)d_in[2];
  const float* gcw = (const float*)d_in[3];
  const float* gcb = (const float*)d_in[4];
  float* out = (float*)d_out;

  char* ws = (char*)d_ws;
  size_t off = 0;
  auto alloc = [&](size_t bytes) -> char* {
    char* p = ws + off;
    off += (bytes + 255) & ~(size_t)255;
    return p;
  };
  short* x1b  = (short*)alloc((size_t)NN * DD * 2);
  short* w1t  = (short*)alloc((size_t)DD * DD * 2);
  short* w2t  = (short*)alloc((size_t)PP * DD * 2);
  short* gcwt = (short*)alloc((size_t)HH * DD * 2);
  short* Y    = (short*)alloc((size_t)NN * DD * 2);
  short* xp   = (short*)alloc((size_t)NN * PP * 2);
  short* hT   = (short*)alloc((size_t)NN * HH * 2);
  float* invnw = (float*)alloc((size_t)NN * 4);
  float* Gp   = (float*)alloc((size_t)128 * PP * HH * 4);
  short* GT   = (short*)alloc((size_t)PP * HH * 2);

  hipLaunchKernelGGL(k_prep, dim3(4192), dim3(256), 0, stream,
                     x1, w1, w2, gcw, x1b, w1t, w2t, gcwt);
  hipLaunchKernelGGL(k_g13, dim3(512), dim3(256), 0, stream, x1b, w1t, gcwt, Y, hT);
  hipLaunchKernelGGL(k_g2e, dim3(128), dim3(256), 0, stream, Y, w2t, hT, xp, invnw, Gp);
  hipLaunchKernelGGL(k_red, dim3(64), dim3(256), 0, stream, Gp, GT);
  hipLaunchKernelGGL(k_gf, dim3(128), dim3(256), 0, stream, xp, GT, invnw, gcb, out);
}